// Round 1
// baseline (5440.017 us; speedup 1.0000x reference)
//
#include <hip/hip_runtime.h>

#define N_NODES 100000
#define N_EDGES 3200000
#define IN_F 256
#define OUT_F 128

// -------------------- Kernel 1: h = x @ w (f32, vector ALU) --------------------
// Block tile: 64 rows x 128 cols. K staged in LDS in chunks of 32.
// 256 threads, each computes 4 rows x 8 cols.
__global__ __launch_bounds__(256) void gemm_xw_kernel(
    const float* __restrict__ x, const float* __restrict__ w,
    float* __restrict__ h)
{
    __shared__ float xs[64][36];    // +4 pad: bank-spread for a-loads, keeps 16B align
    __shared__ float wsh[32][128];

    const int t  = threadIdx.x;
    const int brow = blockIdx.x * 64;
    const int tx = t & 15;          // col group: 16 groups x 8 cols
    const int ty = t >> 4;          // row group: 16 groups x 4 rows

    float acc[4][8];
#pragma unroll
    for (int i = 0; i < 4; ++i)
#pragma unroll
        for (int j = 0; j < 8; ++j) acc[i][j] = 0.f;

    for (int k0 = 0; k0 < IN_F; k0 += 32) {
        // stage x tile: 64 rows x 32 k = 512 float4, 2 per thread (lane-consecutive)
#pragma unroll
        for (int i = 0; i < 2; ++i) {
            int f4 = i * 256 + t;
            int r  = f4 >> 3;
            int kk = (f4 & 7) << 2;
            int gr = brow + r;
            float4 v = make_float4(0.f, 0.f, 0.f, 0.f);
            if (gr < N_NODES)
                v = *(const float4*)(x + (size_t)gr * IN_F + k0 + kk);
            *(float4*)(&xs[r][kk]) = v;   // (r*36+kk)*4 bytes, 16B aligned
        }
        // stage w tile: 32 k x 128 cols = 1024 float4, 4 per thread
#pragma unroll
        for (int i = 0; i < 4; ++i) {
            int f4 = i * 256 + t;
            int kk = f4 >> 5;
            int c  = (f4 & 31) << 2;
            *(float4*)(&wsh[kk][c]) = *(const float4*)(w + (size_t)(k0 + kk) * OUT_F + c);
        }
        __syncthreads();

#pragma unroll
        for (int k = 0; k < 32; ++k) {
            float a[4], b[8];
#pragma unroll
            for (int i = 0; i < 4; ++i) a[i] = xs[ty * 4 + i][k];
#pragma unroll
            for (int j = 0; j < 8; ++j) b[j] = wsh[k][tx * 8 + j];
#pragma unroll
            for (int i = 0; i < 4; ++i)
#pragma unroll
                for (int j = 0; j < 8; ++j) acc[i][j] = fmaf(a[i], b[j], acc[i][j]);
        }
        __syncthreads();
    }

#pragma unroll
    for (int i = 0; i < 4; ++i) {
        int gr = brow + ty * 4 + i;
        if (gr < N_NODES) {
            float* dst = h + (size_t)gr * OUT_F + tx * 8;
            *(float4*)(dst)     = make_float4(acc[i][0], acc[i][1], acc[i][2], acc[i][3]);
            *(float4*)(dst + 4) = make_float4(acc[i][4], acc[i][5], acc[i][6], acc[i][7]);
        }
    }
}

// -------------------- Kernel 2: out[r][f] = bias[f] --------------------
__global__ __launch_bounds__(256) void init_out_kernel(
    const float* __restrict__ bias, float* __restrict__ out)
{
    int gid = blockIdx.x * 256 + threadIdx.x;          // over N_NODES*32 float4s
    if (gid >= N_NODES * (OUT_F / 4)) return;
    int f4 = gid & 31;
    float4 b = ((const float4*)bias)[f4];
    ((float4*)out)[gid] = b;
}

// -------------------- Kernel 3: scatter-add messages --------------------
// One thread per (edge, 4-feature group). 32 threads cover one edge's 128 feats.
__global__ __launch_bounds__(256) void scatter_edges_kernel(
    const int* __restrict__ erow, const int* __restrict__ ecol,
    const float* __restrict__ eval_, const float* __restrict__ h,
    float* __restrict__ out)
{
    int gid = blockIdx.x * 256 + threadIdx.x;          // over N_EDGES*32
    int e  = gid >> 5;
    int f4 = (gid & 31) << 2;
    if (e >= N_EDGES) return;

    int   r = erow[e];
    int   c = ecol[e];
    float v = eval_[e];

    float4 hv = *(const float4*)(h + (size_t)c * OUT_F + f4);
    float* o  = out + (size_t)r * OUT_F + f4;
#if defined(__HIP_DEVICE_COMPILE__)
    unsafeAtomicAdd(o + 0, v * hv.x);   // HW global_atomic_add_f32
    unsafeAtomicAdd(o + 1, v * hv.y);
    unsafeAtomicAdd(o + 2, v * hv.z);
    unsafeAtomicAdd(o + 3, v * hv.w);
#else
    atomicAdd(o + 0, v * hv.x);
    atomicAdd(o + 1, v * hv.y);
    atomicAdd(o + 2, v * hv.z);
    atomicAdd(o + 3, v * hv.w);
#endif
}

// -------------------- launch --------------------
extern "C" void kernel_launch(void* const* d_in, const int* in_sizes, int n_in,
                              void* d_out, int out_size, void* d_ws, size_t ws_size,
                              hipStream_t stream)
{
    const float* x     = (const float*)d_in[0];
    const int*   erow  = (const int*)d_in[1];
    const int*   ecol  = (const int*)d_in[2];
    const float* eval_ = (const float*)d_in[3];
    const float* w     = (const float*)d_in[4];
    const float* bias  = (const float*)d_in[5];
    float*       out   = (float*)d_out;
    float*       h     = (float*)d_ws;    // N_NODES * OUT_F * 4 = 51.2 MB scratch

    // 1) h = x @ w
    hipLaunchKernelGGL(gemm_xw_kernel,
                       dim3((N_NODES + 63) / 64), dim3(256), 0, stream,
                       x, w, h);

    // 2) out = bias (broadcast)
    hipLaunchKernelGGL(init_out_kernel,
                       dim3((N_NODES * (OUT_F / 4) + 255) / 256), dim3(256), 0, stream,
                       bias, out);

    // 3) out[r] += val * h[c]  (atomic scatter)
    hipLaunchKernelGGL(scatter_edges_kernel,
                       dim3((N_EDGES * 32) / 256), dim3(256), 0, stream,
                       erow, ecol, eval_, h, out);
}

// Round 2
// 876.773 us; speedup vs baseline: 6.2046x; 6.2046x over previous
//
#include <hip/hip_runtime.h>

#define N_NODES 100000
#define N_EDGES 3200000
#define IN_F 256
#define OUT_F 128

// -------------------- Kernel 1: h = x @ w (f32, vector ALU) --------------------
// Block tile: 64 rows x 128 cols. K staged in LDS in chunks of 32.
// 256 threads, each computes 4 rows x 8 cols.
__global__ __launch_bounds__(256) void gemm_xw_kernel(
    const float* __restrict__ x, const float* __restrict__ w,
    float* __restrict__ h)
{
    __shared__ float xs[64][36];
    __shared__ float wsh[32][128];

    const int t  = threadIdx.x;
    const int brow = blockIdx.x * 64;
    const int tx = t & 15;
    const int ty = t >> 4;

    float acc[4][8];
#pragma unroll
    for (int i = 0; i < 4; ++i)
#pragma unroll
        for (int j = 0; j < 8; ++j) acc[i][j] = 0.f;

    for (int k0 = 0; k0 < IN_F; k0 += 32) {
#pragma unroll
        for (int i = 0; i < 2; ++i) {
            int f4 = i * 256 + t;
            int r  = f4 >> 3;
            int kk = (f4 & 7) << 2;
            int gr = brow + r;
            float4 v = make_float4(0.f, 0.f, 0.f, 0.f);
            if (gr < N_NODES)
                v = *(const float4*)(x + (size_t)gr * IN_F + k0 + kk);
            *(float4*)(&xs[r][kk]) = v;
        }
#pragma unroll
        for (int i = 0; i < 4; ++i) {
            int f4 = i * 256 + t;
            int kk = f4 >> 5;
            int c  = (f4 & 31) << 2;
            *(float4*)(&wsh[kk][c]) = *(const float4*)(w + (size_t)(k0 + kk) * OUT_F + c);
        }
        __syncthreads();

#pragma unroll
        for (int k = 0; k < 32; ++k) {
            float a[4], b[8];
#pragma unroll
            for (int i = 0; i < 4; ++i) a[i] = xs[ty * 4 + i][k];
#pragma unroll
            for (int j = 0; j < 8; ++j) b[j] = wsh[k][tx * 8 + j];
#pragma unroll
            for (int i = 0; i < 4; ++i)
#pragma unroll
                for (int j = 0; j < 8; ++j) acc[i][j] = fmaf(a[i], b[j], acc[i][j]);
        }
        __syncthreads();
    }

#pragma unroll
    for (int i = 0; i < 4; ++i) {
        int gr = brow + ty * 4 + i;
        if (gr < N_NODES) {
            float* dst = h + (size_t)gr * OUT_F + tx * 8;
            *(float4*)(dst)     = make_float4(acc[i][0], acc[i][1], acc[i][2], acc[i][3]);
            *(float4*)(dst + 4) = make_float4(acc[i][4], acc[i][5], acc[i][6], acc[i][7]);
        }
    }
}

// -------------------- Kernel 2: histogram of edge_row --------------------
__global__ __launch_bounds__(256) void hist_kernel(
    const int* __restrict__ erow, int* __restrict__ cnt)
{
    int e4 = blockIdx.x * 256 + threadIdx.x;     // over N_EDGES/4
    if (e4 >= N_EDGES / 4) return;
    int4 r = ((const int4*)erow)[e4];
    atomicAdd(&cnt[r.x], 1);
    atomicAdd(&cnt[r.y], 1);
    atomicAdd(&cnt[r.z], 1);
    atomicAdd(&cnt[r.w], 1);
}

// -------------------- Kernel 3: exclusive scan (single block) --------------------
__global__ __launch_bounds__(1024) void scan_kernel(
    const int* __restrict__ cnt, int* __restrict__ row_start, int* __restrict__ cursor)
{
    __shared__ int partial[1024];
    const int t = threadIdx.x;
    const int CH = (N_NODES + 1023) / 1024;      // 98
    int lo = t * CH;
    int hi = lo + CH; if (hi > N_NODES) hi = N_NODES;
    int s = 0;
    for (int i = lo; i < hi; ++i) s += cnt[i];
    partial[t] = s;
    __syncthreads();
    // inclusive Hillis-Steele scan in LDS
    for (int off = 1; off < 1024; off <<= 1) {
        int add = (t >= off) ? partial[t - off] : 0;
        __syncthreads();
        partial[t] += add;
        __syncthreads();
    }
    int run = (t == 0) ? 0 : partial[t - 1];     // exclusive base for this chunk
    for (int i = lo; i < hi; ++i) {
        row_start[i] = run;
        cursor[i]    = run;
        run += cnt[i];
    }
}

// -------------------- Kernel 4: permute edges into CSR order --------------------
__global__ __launch_bounds__(256) void permute_kernel(
    const int* __restrict__ erow, const int* __restrict__ ecol,
    const float* __restrict__ eval_, int* __restrict__ cursor,
    int2* __restrict__ packed)
{
    int e = blockIdx.x * 256 + threadIdx.x;
    if (e >= N_EDGES) return;
    int r   = erow[e];
    int pos = atomicAdd(&cursor[r], 1);
    packed[pos] = make_int2(ecol[e], __float_as_int(eval_[e]));
}

// -------------------- Kernel 5: per-row gather-aggregate + bias --------------------
// One 64-lane wave per row; each lane owns 2 output features.
__global__ __launch_bounds__(256) void aggregate_kernel(
    const int2* __restrict__ packed, const int* __restrict__ row_start,
    const int* __restrict__ cnt, const float* __restrict__ h,
    const float* __restrict__ bias, float* __restrict__ out)
{
    int wave = (blockIdx.x * 256 + threadIdx.x) >> 6;
    int lane = threadIdx.x & 63;
    if (wave >= N_NODES) return;

    int start = __builtin_amdgcn_readfirstlane(row_start[wave]);
    int deg   = __builtin_amdgcn_readfirstlane(cnt[wave]);
    int end   = start + deg;

    const float* hb = h + lane * 2;
    float ax = 0.f, ay = 0.f;

    int e = start;
    for (; e + 1 < end; e += 2) {
        int2 p0 = packed[e];
        int2 p1 = packed[e + 1];
        float2 h0 = *(const float2*)(hb + (size_t)p0.x * OUT_F);
        float2 h1 = *(const float2*)(hb + (size_t)p1.x * OUT_F);
        float v0 = __int_as_float(p0.y);
        float v1 = __int_as_float(p1.y);
        ax = fmaf(v0, h0.x, ax); ay = fmaf(v0, h0.y, ay);
        ax = fmaf(v1, h1.x, ax); ay = fmaf(v1, h1.y, ay);
    }
    if (e < end) {
        int2 p0 = packed[e];
        float2 h0 = *(const float2*)(hb + (size_t)p0.x * OUT_F);
        float v0 = __int_as_float(p0.y);
        ax = fmaf(v0, h0.x, ax); ay = fmaf(v0, h0.y, ay);
    }

    float2 b = *(const float2*)(bias + lane * 2);
    *(float2*)(out + (size_t)wave * OUT_F + lane * 2) = make_float2(ax + b.x, ay + b.y);
}

// -------------------- launch --------------------
extern "C" void kernel_launch(void* const* d_in, const int* in_sizes, int n_in,
                              void* d_out, int out_size, void* d_ws, size_t ws_size,
                              hipStream_t stream)
{
    const float* x     = (const float*)d_in[0];
    const int*   erow  = (const int*)d_in[1];
    const int*   ecol  = (const int*)d_in[2];
    const float* eval_ = (const float*)d_in[3];
    const float* w     = (const float*)d_in[4];
    const float* bias  = (const float*)d_in[5];
    float*       out   = (float*)d_out;

    // workspace layout (bytes):
    //   h:         0            .. 51,200,000
    //   cnt:       51,200,000   .. +400,000
    //   row_start: 51,600,000   .. +400,000
    //   cursor:    52,000,000   .. +400,000
    //   packed:    52,400,000   .. +25,600,000   (total 78.0 MB)
    char* ws = (char*)d_ws;
    float* h         = (float*)(ws);
    int*   cnt       = (int*)(ws + 51200000);
    int*   row_start = (int*)(ws + 51600000);
    int*   cursor    = (int*)(ws + 52000000);
    int2*  packed    = (int2*)(ws + 52400000);

    // 0) zero the histogram
    hipMemsetAsync(cnt, 0, N_NODES * sizeof(int), stream);

    // 1) h = x @ w
    hipLaunchKernelGGL(gemm_xw_kernel,
                       dim3((N_NODES + 63) / 64), dim3(256), 0, stream,
                       x, w, h);

    // 2) histogram of rows
    hipLaunchKernelGGL(hist_kernel,
                       dim3((N_EDGES / 4 + 255) / 256), dim3(256), 0, stream,
                       erow, cnt);

    // 3) exclusive scan -> row_start, cursor
    hipLaunchKernelGGL(scan_kernel, dim3(1), dim3(1024), 0, stream,
                       cnt, row_start, cursor);

    // 4) permute edges into CSR order
    hipLaunchKernelGGL(permute_kernel,
                       dim3((N_EDGES + 255) / 256), dim3(256), 0, stream,
                       erow, ecol, eval_, cursor, packed);

    // 5) aggregate rows + bias
    hipLaunchKernelGGL(aggregate_kernel,
                       dim3((N_NODES * 64 + 255) / 256), dim3(256), 0, stream,
                       packed, row_start, cnt, h, bias, out);
}

// Round 3
// 542.166 us; speedup vs baseline: 10.0339x; 1.6172x over previous
//
#include <hip/hip_runtime.h>

#define N_NODES 100000
#define N_EDGES 3200000
#define IN_F 256
#define OUT_F 128

// -------------------- Kernel 1: h = x @ w (f32, vector ALU) --------------------
__global__ __launch_bounds__(256) void gemm_xw_kernel(
    const float* __restrict__ x, const float* __restrict__ w,
    float* __restrict__ h)
{
    __shared__ float xs[64][36];
    __shared__ float wsh[32][128];

    const int t  = threadIdx.x;
    const int brow = blockIdx.x * 64;
    const int tx = t & 15;
    const int ty = t >> 4;

    float acc[4][8];
#pragma unroll
    for (int i = 0; i < 4; ++i)
#pragma unroll
        for (int j = 0; j < 8; ++j) acc[i][j] = 0.f;

    for (int k0 = 0; k0 < IN_F; k0 += 32) {
#pragma unroll
        for (int i = 0; i < 2; ++i) {
            int f4 = i * 256 + t;
            int r  = f4 >> 3;
            int kk = (f4 & 7) << 2;
            int gr = brow + r;
            float4 v = make_float4(0.f, 0.f, 0.f, 0.f);
            if (gr < N_NODES)
                v = *(const float4*)(x + (size_t)gr * IN_F + k0 + kk);
            *(float4*)(&xs[r][kk]) = v;
        }
#pragma unroll
        for (int i = 0; i < 4; ++i) {
            int f4 = i * 256 + t;
            int kk = f4 >> 5;
            int c  = (f4 & 31) << 2;
            *(float4*)(&wsh[kk][c]) = *(const float4*)(w + (size_t)(k0 + kk) * OUT_F + c);
        }
        __syncthreads();

#pragma unroll
        for (int k = 0; k < 32; ++k) {
            float a[4], b[8];
#pragma unroll
            for (int i = 0; i < 4; ++i) a[i] = xs[ty * 4 + i][k];
#pragma unroll
            for (int j = 0; j < 8; ++j) b[j] = wsh[k][tx * 8 + j];
#pragma unroll
            for (int i = 0; i < 4; ++i)
#pragma unroll
                for (int j = 0; j < 8; ++j) acc[i][j] = fmaf(a[i], b[j], acc[i][j]);
        }
        __syncthreads();
    }

#pragma unroll
    for (int i = 0; i < 4; ++i) {
        int gr = brow + ty * 4 + i;
        if (gr < N_NODES) {
            float* dst = h + (size_t)gr * OUT_F + tx * 8;
            *(float4*)(dst)     = make_float4(acc[i][0], acc[i][1], acc[i][2], acc[i][3]);
            *(float4*)(dst + 4) = make_float4(acc[i][4], acc[i][5], acc[i][6], acc[i][7]);
        }
    }
}

// -------------------- Kernel 2: histogram + per-edge rank --------------------
// rank[e] = old count = position of edge e within its row (atomic order).
__global__ __launch_bounds__(256) void hist_kernel(
    const int* __restrict__ erow, int* __restrict__ cnt,
    unsigned short* __restrict__ rank)
{
    int e4 = blockIdx.x * 256 + threadIdx.x;     // over N_EDGES/4
    if (e4 >= N_EDGES / 4) return;
    int4 r = ((const int4*)erow)[e4];
    ushort4 rk;
    rk.x = (unsigned short)atomicAdd(&cnt[r.x], 1);
    rk.y = (unsigned short)atomicAdd(&cnt[r.y], 1);
    rk.z = (unsigned short)atomicAdd(&cnt[r.z], 1);
    rk.w = (unsigned short)atomicAdd(&cnt[r.w], 1);
    ((ushort4*)rank)[e4] = rk;
}

// -------------------- Kernels 3a/3b/3c: 3-phase exclusive scan --------------------
#define SCAN_CHUNK 1024
#define N_SCAN_BLKS ((N_NODES + SCAN_CHUNK - 1) / SCAN_CHUNK)   // 98

__global__ __launch_bounds__(256) void scan_phase1(
    const int* __restrict__ cnt, int* __restrict__ partials)
{
    __shared__ int red[256];
    int t = threadIdx.x, b = blockIdx.x;
    int base = b * SCAN_CHUNK + t * 4;
    int s = 0;
#pragma unroll
    for (int i = 0; i < 4; ++i) {
        int idx = base + i;
        if (idx < N_NODES) s += cnt[idx];
    }
    red[t] = s;
    __syncthreads();
    for (int off = 128; off > 0; off >>= 1) {
        if (t < off) red[t] += red[t + off];
        __syncthreads();
    }
    if (t == 0) partials[b] = red[0];
}

__global__ __launch_bounds__(128) void scan_phase2(int* __restrict__ partials)
{
    __shared__ int sh[128];
    int t = threadIdx.x;
    int v = (t < N_SCAN_BLKS) ? partials[t] : 0;
    sh[t] = v;
    __syncthreads();
    for (int off = 1; off < 128; off <<= 1) {
        int add = (t >= off) ? sh[t - off] : 0;
        __syncthreads();
        sh[t] += add;
        __syncthreads();
    }
    if (t < N_SCAN_BLKS) partials[t] = sh[t] - v;    // exclusive
}

__global__ __launch_bounds__(256) void scan_phase3(
    const int* __restrict__ cnt, const int* __restrict__ partials,
    int* __restrict__ row_start)
{
    __shared__ int sh[256];
    int t = threadIdx.x, b = blockIdx.x;
    int base = b * SCAN_CHUNK + t * 4;
    int c[4];
    int s = 0;
#pragma unroll
    for (int i = 0; i < 4; ++i) {
        int idx = base + i;
        c[i] = (idx < N_NODES) ? cnt[idx] : 0;
        s += c[i];
    }
    sh[t] = s;
    __syncthreads();
    for (int off = 1; off < 256; off <<= 1) {
        int add = (t >= off) ? sh[t - off] : 0;
        __syncthreads();
        sh[t] += add;
        __syncthreads();
    }
    int run = sh[t] - s + partials[b];    // exclusive base for this thread
#pragma unroll
    for (int i = 0; i < 4; ++i) {
        int idx = base + i;
        if (idx < N_NODES) { row_start[idx] = run; run += c[i]; }
    }
}

// -------------------- Kernel 4: atomic-free permute into CSR order --------------------
__global__ __launch_bounds__(256) void permute_kernel(
    const int* __restrict__ erow, const int* __restrict__ ecol,
    const float* __restrict__ eval_, const unsigned short* __restrict__ rank,
    const int* __restrict__ row_start, int2* __restrict__ packed)
{
    int e = blockIdx.x * 256 + threadIdx.x;
    if (e >= N_EDGES) return;
    int r   = erow[e];
    int pos = row_start[r] + (int)rank[e];
    packed[pos] = make_int2(ecol[e], __float_as_int(eval_[e]));
}

// -------------------- Kernel 5: per-row gather-aggregate + bias --------------------
// One 64-lane wave per row; each lane owns 2 output features. Unroll 4 edges.
__global__ __launch_bounds__(256) void aggregate_kernel(
    const int2* __restrict__ packed, const int* __restrict__ row_start,
    const int* __restrict__ cnt, const float* __restrict__ h,
    const float* __restrict__ bias, float* __restrict__ out)
{
    int wave = (blockIdx.x * 256 + threadIdx.x) >> 6;
    int lane = threadIdx.x & 63;
    if (wave >= N_NODES) return;

    int start = __builtin_amdgcn_readfirstlane(row_start[wave]);
    int deg   = __builtin_amdgcn_readfirstlane(cnt[wave]);
    int end   = start + deg;

    const float* hb = h + lane * 2;
    float ax = 0.f, ay = 0.f;

    int e = start;
    for (; e + 3 < end; e += 4) {
        int2 p0 = packed[e];
        int2 p1 = packed[e + 1];
        int2 p2 = packed[e + 2];
        int2 p3 = packed[e + 3];
        float2 h0 = *(const float2*)(hb + (size_t)p0.x * OUT_F);
        float2 h1 = *(const float2*)(hb + (size_t)p1.x * OUT_F);
        float2 h2 = *(const float2*)(hb + (size_t)p2.x * OUT_F);
        float2 h3 = *(const float2*)(hb + (size_t)p3.x * OUT_F);
        float v0 = __int_as_float(p0.y), v1 = __int_as_float(p1.y);
        float v2 = __int_as_float(p2.y), v3 = __int_as_float(p3.y);
        ax = fmaf(v0, h0.x, ax); ay = fmaf(v0, h0.y, ay);
        ax = fmaf(v1, h1.x, ax); ay = fmaf(v1, h1.y, ay);
        ax = fmaf(v2, h2.x, ax); ay = fmaf(v2, h2.y, ay);
        ax = fmaf(v3, h3.x, ax); ay = fmaf(v3, h3.y, ay);
    }
    for (; e < end; ++e) {
        int2 p0 = packed[e];
        float2 h0 = *(const float2*)(hb + (size_t)p0.x * OUT_F);
        float v0 = __int_as_float(p0.y);
        ax = fmaf(v0, h0.x, ax); ay = fmaf(v0, h0.y, ay);
    }

    float2 b = *(const float2*)(bias + lane * 2);
    *(float2*)(out + (size_t)wave * OUT_F + lane * 2) = make_float2(ax + b.x, ay + b.y);
}

// -------------------- launch --------------------
extern "C" void kernel_launch(void* const* d_in, const int* in_sizes, int n_in,
                              void* d_out, int out_size, void* d_ws, size_t ws_size,
                              hipStream_t stream)
{
    const float* x     = (const float*)d_in[0];
    const int*   erow  = (const int*)d_in[1];
    const int*   ecol  = (const int*)d_in[2];
    const float* eval_ = (const float*)d_in[3];
    const float* w     = (const float*)d_in[4];
    const float* bias  = (const float*)d_in[5];
    float*       out   = (float*)d_out;

    // workspace layout (bytes):
    //   h:         0            .. 51,200,000
    //   cnt:       51,200,000   .. +400,000
    //   row_start: 51,600,000   .. +400,000
    //   partials:  52,000,000   .. +4,096 (98 ints, padded)
    //   rank:      52,004,096   .. +6,400,000   (ushort per edge)
    //   packed:    58,404,096   .. +25,600,000  (total ~84.0 MB)
    char* ws = (char*)d_ws;
    float*          h         = (float*)(ws);
    int*            cnt       = (int*)(ws + 51200000);
    int*            row_start = (int*)(ws + 51600000);
    int*            partials  = (int*)(ws + 52000000);
    unsigned short* rank      = (unsigned short*)(ws + 52004096);
    int2*           packed    = (int2*)(ws + 58404096);

    // 0) zero the histogram
    hipMemsetAsync(cnt, 0, N_NODES * sizeof(int), stream);

    // 1) h = x @ w
    hipLaunchKernelGGL(gemm_xw_kernel,
                       dim3((N_NODES + 63) / 64), dim3(256), 0, stream,
                       x, w, h);

    // 2) histogram + rank
    hipLaunchKernelGGL(hist_kernel,
                       dim3((N_EDGES / 4 + 255) / 256), dim3(256), 0, stream,
                       erow, cnt, rank);

    // 3) exclusive scan -> row_start
    hipLaunchKernelGGL(scan_phase1, dim3(N_SCAN_BLKS), dim3(256), 0, stream, cnt, partials);
    hipLaunchKernelGGL(scan_phase2, dim3(1), dim3(128), 0, stream, partials);
    hipLaunchKernelGGL(scan_phase3, dim3(N_SCAN_BLKS), dim3(256), 0, stream,
                       cnt, partials, row_start);

    // 4) atomic-free permute into CSR order
    hipLaunchKernelGGL(permute_kernel,
                       dim3((N_EDGES + 255) / 256), dim3(256), 0, stream,
                       erow, ecol, eval_, rank, row_start, packed);

    // 5) aggregate rows + bias
    hipLaunchKernelGGL(aggregate_kernel,
                       dim3((N_NODES * 64 + 255) / 256), dim3(256), 0, stream,
                       packed, row_start, cnt, h, bias, out);
}

// Round 4
// 339.331 us; speedup vs baseline: 16.0316x; 1.5977x over previous
//
#include <hip/hip_runtime.h>

#define N_NODES 100000
#define N_EDGES 3200000
#define IN_F 256
#define OUT_F 128

typedef __attribute__((ext_vector_type(8))) short bf16x8;
typedef __attribute__((ext_vector_type(4))) float f32x4;

__device__ inline unsigned short f2bf(float f) {
    union { float f; unsigned u; } v; v.f = f;
    unsigned r = v.u + 0x7FFFu + ((v.u >> 16) & 1u);   // round-to-nearest-even
    return (unsigned short)(r >> 16);
}
__device__ inline unsigned pk2(float a, float b) {
    return (unsigned)f2bf(a) | ((unsigned)f2bf(b) << 16);
}

// -------------------- Kernel 1: h = bf16(x @ w) via MFMA --------------------
// Block: 256 threads = 4 waves. Tile: 128 rows x 128 cols, K staged 32/step.
// Wave w computes rows [w*32, w*32+32) x all 128 cols: 2x8 fragments of 16x16x32.
__global__ __launch_bounds__(256) void gemm_xw_mfma(
    const float* __restrict__ x, const float* __restrict__ w,
    unsigned short* __restrict__ h)   // h: bf16 bits [N_NODES][128]
{
    __shared__ unsigned short alds[128][40];    // 80 B/row (pad 32->40): 2-way max on b128 reads
    __shared__ unsigned short blds[128][264];   // [col][k] 528 B/row: 2-way max

    const int t    = threadIdx.x;
    const int lane = t & 63;
    const int wid  = t >> 6;
    const int brow = blockIdx.x * 128;
    const int ln   = lane & 15;
    const int kb   = lane >> 4;       // 0..3
    const int am   = wid * 32;

    // ---- one-time: stage w transposed to bf16 in LDS ----
    // thread t: c4 = (t&31)*4 cols, k rows (t>>5)*4 + kb2*32
    {
        int c4 = (t & 31) * 4;
        int kr = (t >> 5) * 4;
#pragma unroll
        for (int kb2 = 0; kb2 < 8; ++kb2) {
            int kbase = kb2 * 32 + kr;
            float4 r0 = *(const float4*)(w + (size_t)(kbase + 0) * OUT_F + c4);
            float4 r1 = *(const float4*)(w + (size_t)(kbase + 1) * OUT_F + c4);
            float4 r2 = *(const float4*)(w + (size_t)(kbase + 2) * OUT_F + c4);
            float4 r3 = *(const float4*)(w + (size_t)(kbase + 3) * OUT_F + c4);
            // transpose 4x4: write 4 consecutive k per col
            *(uint2*)&blds[c4 + 0][kbase] = make_uint2(pk2(r0.x, r1.x), pk2(r2.x, r3.x));
            *(uint2*)&blds[c4 + 1][kbase] = make_uint2(pk2(r0.y, r1.y), pk2(r2.y, r3.y));
            *(uint2*)&blds[c4 + 2][kbase] = make_uint2(pk2(r0.z, r1.z), pk2(r2.z, r3.z));
            *(uint2*)&blds[c4 + 3][kbase] = make_uint2(pk2(r0.w, r1.w), pk2(r2.w, r3.w));
        }
    }

    f32x4 acc[2][8] = {};

    for (int k0 = 0; k0 < IN_F; k0 += 32) {
        // ---- stage A tile: 128 rows x 32 k, f32 -> bf16 ----
        {
            int r  = t >> 1;
            int kh = (t & 1) * 16;
            int gr = brow + r;
            float f[16];
#pragma unroll
            for (int i = 0; i < 16; ++i) f[i] = 0.f;
            if (gr < N_NODES) {
                const float* src = x + (size_t)gr * IN_F + k0 + kh;
                *(float4*)&f[0]  = ((const float4*)src)[0];
                *(float4*)&f[4]  = ((const float4*)src)[1];
                *(float4*)&f[8]  = ((const float4*)src)[2];
                *(float4*)&f[12] = ((const float4*)src)[3];
            }
            uint4 qa, qb;
            qa.x = pk2(f[0], f[1]);   qa.y = pk2(f[2], f[3]);
            qa.z = pk2(f[4], f[5]);   qa.w = pk2(f[6], f[7]);
            qb.x = pk2(f[8], f[9]);   qb.y = pk2(f[10], f[11]);
            qb.z = pk2(f[12], f[13]); qb.w = pk2(f[14], f[15]);
            *(uint4*)&alds[r][kh]     = qa;
            *(uint4*)&alds[r][kh + 8] = qb;
        }
        __syncthreads();    // also fences the one-time w staging before first use

        bf16x8 a[2], b[8];
#pragma unroll
        for (int fm = 0; fm < 2; ++fm)
            a[fm] = *(const bf16x8*)&alds[am + fm * 16 + ln][kb * 8];
#pragma unroll
        for (int fn = 0; fn < 8; ++fn)
            b[fn] = *(const bf16x8*)&blds[fn * 16 + ln][k0 + kb * 8];

#pragma unroll
        for (int fm = 0; fm < 2; ++fm)
#pragma unroll
            for (int fn = 0; fn < 8; ++fn)
                acc[fm][fn] = __builtin_amdgcn_mfma_f32_16x16x32_bf16(
                    a[fm], b[fn], acc[fm][fn], 0, 0, 0);
        __syncthreads();
    }

    // ---- epilogue: C/D layout col=lane&15, row=(lane>>4)*4+reg ----
#pragma unroll
    for (int fm = 0; fm < 2; ++fm) {
#pragma unroll
        for (int r = 0; r < 4; ++r) {
            int grow = brow + am + fm * 16 + (lane >> 4) * 4 + r;
            if (grow < N_NODES) {
                unsigned short* dst = h + (size_t)grow * OUT_F + ln;
#pragma unroll
                for (int fn = 0; fn < 8; ++fn)
                    dst[fn * 16] = f2bf(acc[fm][fn][r]);
            }
        }
    }
}

// -------------------- Kernel 2: histogram + per-edge rank --------------------
__global__ __launch_bounds__(256) void hist_kernel(
    const int* __restrict__ erow, int* __restrict__ cnt,
    unsigned short* __restrict__ rank)
{
    int e4 = blockIdx.x * 256 + threadIdx.x;
    if (e4 >= N_EDGES / 4) return;
    int4 r = ((const int4*)erow)[e4];
    ushort4 rk;
    rk.x = (unsigned short)atomicAdd(&cnt[r.x], 1);
    rk.y = (unsigned short)atomicAdd(&cnt[r.y], 1);
    rk.z = (unsigned short)atomicAdd(&cnt[r.z], 1);
    rk.w = (unsigned short)atomicAdd(&cnt[r.w], 1);
    ((ushort4*)rank)[e4] = rk;
}

// -------------------- Kernels 3a/3b/3c: 3-phase exclusive scan --------------------
#define SCAN_CHUNK 1024
#define N_SCAN_BLKS ((N_NODES + SCAN_CHUNK - 1) / SCAN_CHUNK)   // 98

__global__ __launch_bounds__(256) void scan_phase1(
    const int* __restrict__ cnt, int* __restrict__ partials)
{
    __shared__ int red[256];
    int t = threadIdx.x, b = blockIdx.x;
    int base = b * SCAN_CHUNK + t * 4;
    int s = 0;
#pragma unroll
    for (int i = 0; i < 4; ++i) {
        int idx = base + i;
        if (idx < N_NODES) s += cnt[idx];
    }
    red[t] = s;
    __syncthreads();
    for (int off = 128; off > 0; off >>= 1) {
        if (t < off) red[t] += red[t + off];
        __syncthreads();
    }
    if (t == 0) partials[b] = red[0];
}

__global__ __launch_bounds__(128) void scan_phase2(int* __restrict__ partials)
{
    __shared__ int sh[128];
    int t = threadIdx.x;
    int v = (t < N_SCAN_BLKS) ? partials[t] : 0;
    sh[t] = v;
    __syncthreads();
    for (int off = 1; off < 128; off <<= 1) {
        int add = (t >= off) ? sh[t - off] : 0;
        __syncthreads();
        sh[t] += add;
        __syncthreads();
    }
    if (t < N_SCAN_BLKS) partials[t] = sh[t] - v;    // exclusive
}

__global__ __launch_bounds__(256) void scan_phase3(
    const int* __restrict__ cnt, const int* __restrict__ partials,
    int* __restrict__ row_start)
{
    __shared__ int sh[256];
    int t = threadIdx.x, b = blockIdx.x;
    int base = b * SCAN_CHUNK + t * 4;
    int c[4];
    int s = 0;
#pragma unroll
    for (int i = 0; i < 4; ++i) {
        int idx = base + i;
        c[i] = (idx < N_NODES) ? cnt[idx] : 0;
        s += c[i];
    }
    sh[t] = s;
    __syncthreads();
    for (int off = 1; off < 256; off <<= 1) {
        int add = (t >= off) ? sh[t - off] : 0;
        __syncthreads();
        sh[t] += add;
        __syncthreads();
    }
    int run = sh[t] - s + partials[b];
#pragma unroll
    for (int i = 0; i < 4; ++i) {
        int idx = base + i;
        if (idx < N_NODES) { row_start[idx] = run; run += c[i]; }
    }
}

// -------------------- Kernel 4: atomic-free permute into CSR order --------------------
__global__ __launch_bounds__(256) void permute_kernel(
    const int* __restrict__ erow, const int* __restrict__ ecol,
    const float* __restrict__ eval_, const unsigned short* __restrict__ rank,
    const int* __restrict__ row_start, int2* __restrict__ packed)
{
    int e = blockIdx.x * 256 + threadIdx.x;
    if (e >= N_EDGES) return;
    int r   = erow[e];
    int pos = row_start[r] + (int)rank[e];
    packed[pos] = make_int2(ecol[e], __float_as_int(eval_[e]));
}

// -------------------- Kernel 5: per-row gather-aggregate + bias --------------------
// One wave per row; lane owns feats {2*lane, 2*lane+1} = one uint (2 bf16) per h row.
__global__ __launch_bounds__(256) void aggregate_kernel(
    const int2* __restrict__ packed, const int* __restrict__ row_start,
    const int* __restrict__ cnt, const unsigned* __restrict__ h2,
    const float* __restrict__ bias, float* __restrict__ out)
{
    int wave = (blockIdx.x * 256 + threadIdx.x) >> 6;
    int lane = threadIdx.x & 63;
    if (wave >= N_NODES) return;

    int start = __builtin_amdgcn_readfirstlane(row_start[wave]);
    int deg   = __builtin_amdgcn_readfirstlane(cnt[wave]);
    int end   = start + deg;

    const unsigned* hb = h2 + lane;   // lane-th uint of each 64-uint row
    float ax = 0.f, ay = 0.f;

    int e = start;
    for (; e + 3 < end; e += 4) {
        int2 p0 = packed[e];
        int2 p1 = packed[e + 1];
        int2 p2 = packed[e + 2];
        int2 p3 = packed[e + 3];
        unsigned u0 = hb[(size_t)p0.x << 6];
        unsigned u1 = hb[(size_t)p1.x << 6];
        unsigned u2 = hb[(size_t)p2.x << 6];
        unsigned u3 = hb[(size_t)p3.x << 6];
        float v0 = __int_as_float(p0.y), v1 = __int_as_float(p1.y);
        float v2 = __int_as_float(p2.y), v3 = __int_as_float(p3.y);
        ax = fmaf(v0, __uint_as_float(u0 << 16), ax);
        ay = fmaf(v0, __uint_as_float(u0 & 0xFFFF0000u), ay);
        ax = fmaf(v1, __uint_as_float(u1 << 16), ax);
        ay = fmaf(v1, __uint_as_float(u1 & 0xFFFF0000u), ay);
        ax = fmaf(v2, __uint_as_float(u2 << 16), ax);
        ay = fmaf(v2, __uint_as_float(u2 & 0xFFFF0000u), ay);
        ax = fmaf(v3, __uint_as_float(u3 << 16), ax);
        ay = fmaf(v3, __uint_as_float(u3 & 0xFFFF0000u), ay);
    }
    for (; e < end; ++e) {
        int2 p0 = packed[e];
        unsigned u0 = hb[(size_t)p0.x << 6];
        float v0 = __int_as_float(p0.y);
        ax = fmaf(v0, __uint_as_float(u0 << 16), ax);
        ay = fmaf(v0, __uint_as_float(u0 & 0xFFFF0000u), ay);
    }

    float2 b = *(const float2*)(bias + lane * 2);
    *(float2*)(out + (size_t)wave * OUT_F + lane * 2) = make_float2(ax + b.x, ay + b.y);
}

// -------------------- launch --------------------
extern "C" void kernel_launch(void* const* d_in, const int* in_sizes, int n_in,
                              void* d_out, int out_size, void* d_ws, size_t ws_size,
                              hipStream_t stream)
{
    const float* x     = (const float*)d_in[0];
    const int*   erow  = (const int*)d_in[1];
    const int*   ecol  = (const int*)d_in[2];
    const float* eval_ = (const float*)d_in[3];
    const float* w     = (const float*)d_in[4];
    const float* bias  = (const float*)d_in[5];
    float*       out   = (float*)d_out;

    // workspace layout (bytes):
    //   h (bf16):  0            .. 25,600,000
    //   cnt:       25,600,000   .. +400,000
    //   row_start: 26,000,000   .. +400,000
    //   partials:  26,400,000   .. +4,096
    //   rank:      26,404,096   .. +6,400,000
    //   packed:    32,804,096   .. +25,600,000   (total ~58.4 MB)
    char* ws = (char*)d_ws;
    unsigned short* h         = (unsigned short*)(ws);
    int*            cnt       = (int*)(ws + 25600000);
    int*            row_start = (int*)(ws + 26000000);
    int*            partials  = (int*)(ws + 26400000);
    unsigned short* rank      = (unsigned short*)(ws + 26404096);
    int2*           packed    = (int2*)(ws + 32804096);

    hipMemsetAsync(cnt, 0, N_NODES * sizeof(int), stream);

    // 1) h = bf16(x @ w) via MFMA
    hipLaunchKernelGGL(gemm_xw_mfma,
                       dim3((N_NODES + 127) / 128), dim3(256), 0, stream,
                       x, w, h);

    // 2) histogram + rank
    hipLaunchKernelGGL(hist_kernel,
                       dim3((N_EDGES / 4 + 255) / 256), dim3(256), 0, stream,
                       erow, cnt, rank);

    // 3) exclusive scan -> row_start
    hipLaunchKernelGGL(scan_phase1, dim3(N_SCAN_BLKS), dim3(256), 0, stream, cnt, partials);
    hipLaunchKernelGGL(scan_phase2, dim3(1), dim3(128), 0, stream, partials);
    hipLaunchKernelGGL(scan_phase3, dim3(N_SCAN_BLKS), dim3(256), 0, stream,
                       cnt, partials, row_start);

    // 4) atomic-free permute into CSR order
    hipLaunchKernelGGL(permute_kernel,
                       dim3((N_EDGES + 255) / 256), dim3(256), 0, stream,
                       erow, ecol, eval_, rank, row_start, packed);

    // 5) aggregate rows + bias
    hipLaunchKernelGGL(aggregate_kernel,
                       dim3((N_NODES * 64 + 255) / 256), dim3(256), 0, stream,
                       packed, row_start, cnt, (const unsigned*)h, bias, out);
}